// Round 4
// baseline (55.683 us; speedup 1.0000x reference)
//
#include <hip/hip_runtime.h>
#include <math.h>

#define NPIX   614400   // 8*240*320
#define HW     76800
#define NBATCH 8
#define NB     256
#define NEDGE  257
#define ELEMS  4
#define MAIN_BLOCKS (NPIX / (256 * ELEMS))   // 600
#define BPB (MAIN_BLOCKS / NBATCH)           // 75 blocks per batch
#define FINF 3.402823466e+38f

// ws layout (memset 0 over [0,8256) each call):
//   [0,40)       double sums[5]: {cnt, sumsq, sumd, sumd2, dir2}
//   [40,44)      uint ticket
//   [64,8256)    uint gD[8][256]  complement-space bracket mins (0 = +inf)
//   [8256,16448) float cs[8][256] sorted centers (fully rewritten each call)

__device__ __forceinline__ double wsum64(double v) {
#pragma unroll
  for (int o = 32; o > 0; o >>= 1) v += __shfl_down(v, o, 64);
  return v;
}

__device__ __forceinline__ unsigned int nzb(unsigned int w) {
  return ((w & 0xFFu) != 0u) + (((w >> 8) & 0xFFu) != 0u) +
         (((w >> 16) & 0xFFu) != 0u) + ((w >> 24) != 0u);
}

__global__ void __launch_bounds__(256) k_fused(
    const float* __restrict__ p, const float* __restrict__ t,
    const void* __restrict__ mask, const float* __restrict__ edges,
    double* __restrict__ sums, unsigned int* __restrict__ ticket,
    unsigned int* __restrict__ gD, float* __restrict__ cs,
    float* __restrict__ out) {
  __shared__ float c_lds[NB];
  __shared__ unsigned int d_lds[NB];
  __shared__ double shred[4][5];
  __shared__ unsigned int sh_u[4];
  __shared__ unsigned int last_flag;

  const int tid = threadIdx.x;
  const int lane = tid & 63, wid = tid >> 6;
  const int b = blockIdx.x / BPB;
  const int base = blockIdx.x * (256 * ELEMS) + tid * ELEMS;

  // issue the big streaming loads first
  const float4 p4 = *(const float4*)(p + base);
  const float4 t4 = *(const float4*)(t + base);

  // ---- mask dtype detect from first 4KB (same for every block) ----
  uint4 raw = ((const uint4*)mask)[tid];
  unsigned int cnz = nzb(raw.x) + nzb(raw.y) + nzb(raw.z) + nzb(raw.w);
#pragma unroll
  for (int o = 32; o > 0; o >>= 1) cnz += __shfl_down(cnz, o, 64);
  if (lane == 0) sh_u[wid] = cnz;
  __syncthreads();
  // bool(1B): ~2048/4096 nonzero bytes; int32: ~512/4096
  const bool bytemode = (sh_u[0] + sh_u[1] + sh_u[2] + sh_u[3]) > 1024u;

  // ---- bitonic sort of this batch's 256 centers (shfl; LDS only j>=64) ----
  float v = 0.5f * (edges[b * NEDGE + tid] + edges[b * NEDGE + tid + 1]);
  for (int k = 2; k <= NB; k <<= 1) {
    for (int j = k >> 1; j > 0; j >>= 1) {
      float partner;
      if (j < 64) {
        partner = __shfl_xor(v, j, 64);
      } else {
        __syncthreads();
        c_lds[tid] = v;
        __syncthreads();
        partner = c_lds[tid ^ j];
      }
      const bool up = ((tid & k) == 0);
      const bool low = ((tid & j) == 0);
      v = (low == up) ? fminf(v, partner) : fmaxf(v, partner);
    }
  }
  __syncthreads();
  c_lds[tid] = v;
  d_lds[tid] = 0u;   // complement space: 0 == +inf
  __syncthreads();

  // ---- main body: masked sums + chamfer scatter ----
  float pe[ELEMS] = {p4.x, p4.y, p4.z, p4.w};
  float te[ELEMS] = {t4.x, t4.y, t4.z, t4.w};
  int me[ELEMS];
  if (bytemode) {
    uchar4 m4 = *(const uchar4*)((const unsigned char*)mask + base);
    me[0] = m4.x; me[1] = m4.y; me[2] = m4.z; me[3] = m4.w;
  } else {
    int4 m4 = *(const int4*)((const int*)mask + base);
    me[0] = m4.x; me[1] = m4.y; me[2] = m4.z; me[3] = m4.w;
  }

  double cnt = 0, ssq = 0, sd = 0, sd2 = 0, dir2 = 0;
#pragma unroll
  for (int e = 0; e < ELEMS; ++e) {
    const float pi = pe[e], ti = te[e];
    if (me[e]) {
      float diff = pi - ti;
      float d = logf(pi + 1e-10f) - logf(ti + 1e-10f);
      cnt += 1.0;
      ssq += (double)diff * (double)diff;
      sd  += (double)d;
      sd2 += (double)d * (double)d;
    }
    // largest k with c[k] <= ti
    int k = -1;
#pragma unroll
    for (int s = 128; s > 0; s >>= 1) {
      int nk = k + s;
      if (nk < NB && c_lds[nk] <= ti) k = nk;
    }
    float dl = (k >= 0)     ? ti - c_lds[k]     : 1e30f;
    float dr = (k + 1 < NB) ? c_lds[k + 1] - ti : 1e30f;
    if (k >= 0)     atomicMax(&d_lds[k],     ~__float_as_uint(dl));
    if (k + 1 < NB) atomicMax(&d_lds[k + 1], ~__float_as_uint(dr));
    float dmin = fminf(dl, dr);
    dir2 += (double)dmin * (double)dmin;
  }

  __syncthreads();
  {
    unsigned int dv = d_lds[tid];
    if (dv) atomicMax(&gD[b * NB + tid], dv);
  }
  if ((blockIdx.x % BPB) == 0) {
    atomicExch(&cs[b * NB + tid], c_lds[tid]);   // publish sorted centers
  }

  double acc[5] = {cnt, ssq, sd, sd2, dir2};
#pragma unroll
  for (int i = 0; i < 5; ++i) {
    double r = wsum64(acc[i]);
    if (lane == 0) shred[wid][i] = r;
  }
  __syncthreads();
  if (tid < 5) {
    atomicAdd(&sums[tid],
              shred[0][tid] + shred[1][tid] + shred[2][tid] + shred[3][tid]);
  }

  // ---- ticket: last block finalizes ----
  __threadfence();
  __syncthreads();
  if (tid == 0)
    last_flag = (atomicAdd(ticket, 1u) == (unsigned)(MAIN_BLOCKS - 1)) ? 1u : 0u;
  __syncthreads();
  if (last_flag == 0u) return;
  __threadfence();

  double dir1 = 0.0;
#pragma unroll
  for (int r = 0; r < 2; ++r) {
    const int bb = wid + r * 4;
    float c[4], D[4];
#pragma unroll
    for (int i = 0; i < 4; ++i) {
      const int idx = bb * NB + lane * 4 + i;
      c[i] = __uint_as_float(atomicOr((unsigned int*)&cs[idx], 0u));
      unsigned int s = atomicOr(&gD[idx], 0u);
      D[i] = s ? __uint_as_float(~s) : FINF;
    }

    // prefix-inclusive min of (D - c)
    float pa[4];
    pa[0] = D[0] - c[0];
    pa[1] = fminf(pa[0], D[1] - c[1]);
    pa[2] = fminf(pa[1], D[2] - c[2]);
    pa[3] = fminf(pa[2], D[3] - c[3]);
    float s1 = pa[3];
#pragma unroll
    for (int off = 1; off < 64; off <<= 1) {
      float u = __shfl_up(s1, off, 64);
      if (lane >= off) s1 = fminf(s1, u);
    }
    float exL = __shfl_up(s1, 1, 64);
    if (lane == 0) exL = FINF;

    // suffix-inclusive min of (D + c)
    float sb[4];
    sb[3] = D[3] + c[3];
    sb[2] = fminf(sb[3], D[2] + c[2]);
    sb[1] = fminf(sb[2], D[1] + c[1]);
    sb[0] = fminf(sb[1], D[0] + c[0]);
    float s2 = sb[0];
#pragma unroll
    for (int off = 1; off < 64; off <<= 1) {
      float u = __shfl_down(s2, off, 64);
      if (lane + off < 64) s2 = fminf(s2, u);
    }
    float exR = __shfl_down(s2, 1, 64);
    if (lane == 63) exR = FINF;

#pragma unroll
    for (int i = 0; i < 4; ++i) {
      float pref = fminf(exL, pa[i]);
      float suf  = fminf(exR, sb[i]);
      float dist = fminf(pref + c[i], suf - c[i]);
      dir1 += (double)dist * (double)dist;
    }
  }

  dir1 = wsum64(dir1);
  if (lane == 0) shred[wid][0] = dir1;
  __syncthreads();
  if (tid == 0) {
    double d1 = shred[0][0] + shred[1][0] + shred[2][0] + shred[3][0];
    double cnt_ = atomicAdd(&sums[0], 0.0);
    double ssq_ = atomicAdd(&sums[1], 0.0);
    double sd_  = atomicAdd(&sums[2], 0.0);
    double sd2_ = atomicAdd(&sums[3], 0.0);
    double d2_  = atomicAdd(&sums[4], 0.0);
    double l2 = sqrt(ssq_ / cnt_);
    double dm = sd_ / cnt_, d2m = sd2_ / cnt_;
    double silog = 10.0 * sqrt(d2m - 0.85 * dm * dm);
    double chamfer = (d1 + d2_) / (double)NBATCH;
    out[0] = (float)(l2 + silog + chamfer);
  }
}

extern "C" void kernel_launch(void* const* d_in, const int* in_sizes, int n_in,
                              void* d_out, int out_size, void* d_ws, size_t ws_size,
                              hipStream_t stream) {
  const float* pred  = (const float*)d_in[0];
  const float* targ  = (const float*)d_in[1];
  const float* edges = (const float*)d_in[2];
  const void*  mask  = d_in[3];

  char* ws = (char*)d_ws;
  double* sums         = (double*)ws;
  unsigned int* ticket = (unsigned int*)(ws + 40);
  unsigned int* gD     = (unsigned int*)(ws + 64);
  float* cs            = (float*)(ws + 8256);

  hipMemsetAsync(ws, 0, 8256, stream);
  k_fused<<<MAIN_BLOCKS, NB, 0, stream>>>(pred, targ, mask, edges,
                                          sums, ticket, gD, cs, (float*)d_out);
}

// Round 5
// 34.829 us; speedup vs baseline: 1.5988x; 1.5988x over previous
//
#include <hip/hip_runtime.h>
#include <math.h>

#define NPIX   614400   // 8*240*320
#define HW     76800
#define NBATCH 8
#define NB     256
#define NEDGE  257
#define ELEMS  4
#define MAIN_BLOCKS (NPIX / (256 * ELEMS))   // 600
#define BPB (MAIN_BLOCKS / NBATCH)           // 75 blocks per batch
#define FINF 3.402823466e+38f

// ws layout (memset 0 over [0,8256) each call):
//   [0,40)       double sums[5]: {cnt, sumsq, sumd, sumd2, dir2}
//   [40,44)      uint ticket
//   [64,8256)    uint gD[8][256]  complement-space bracket mins (0 = +inf)
//   [8256,16448) float cs[8][256] sorted centers (published via atomicExch)
//
// All cross-block traffic is ATOMIC (coherent at the device coherence point);
// ordering before the ticket needs only s_waitcnt vmcnt(0), NOT __threadfence()
// (agent fence on gfx950 = buffer_wbl2 L2-writeback, ~30us across 600 blocks).

__device__ __forceinline__ double wsum64(double v) {
#pragma unroll
  for (int o = 32; o > 0; o >>= 1) v += __shfl_down(v, o, 64);
  return v;
}

__device__ __forceinline__ unsigned int nzb(unsigned int w) {
  return ((w & 0xFFu) != 0u) + (((w >> 8) & 0xFFu) != 0u) +
         (((w >> 16) & 0xFFu) != 0u) + ((w >> 24) != 0u);
}

__global__ void __launch_bounds__(256) k_fused(
    const float* __restrict__ p, const float* __restrict__ t,
    const void* __restrict__ mask, const float* __restrict__ edges,
    double* __restrict__ sums, unsigned int* __restrict__ ticket,
    unsigned int* __restrict__ gD, float* __restrict__ cs,
    float* __restrict__ out) {
  __shared__ float c_lds[NB];
  __shared__ unsigned int d_lds[NB];
  __shared__ double shred[4][5];
  __shared__ unsigned int sh_u[4];
  __shared__ unsigned int last_flag;

  const int tid = threadIdx.x;
  const int lane = tid & 63, wid = tid >> 6;
  const int b = blockIdx.x / BPB;
  const int base = blockIdx.x * (256 * ELEMS) + tid * ELEMS;

  // issue the big streaming loads first
  const float4 p4 = *(const float4*)(p + base);
  const float4 t4 = *(const float4*)(t + base);

  // ---- mask dtype detect from first 4KB (same result in every block) ----
  uint4 raw = ((const uint4*)mask)[tid];
  unsigned int cnz = nzb(raw.x) + nzb(raw.y) + nzb(raw.z) + nzb(raw.w);
#pragma unroll
  for (int o = 32; o > 0; o >>= 1) cnz += __shfl_down(cnz, o, 64);
  if (lane == 0) sh_u[wid] = cnz;
  __syncthreads();
  // bool(1B): ~2048/4096 nonzero bytes; int32: ~512/4096
  const bool bytemode = (sh_u[0] + sh_u[1] + sh_u[2] + sh_u[3]) > 1024u;

  // ---- bitonic sort of this batch's 256 centers (shfl; LDS only j>=64) ----
  float v = 0.5f * (edges[b * NEDGE + tid] + edges[b * NEDGE + tid + 1]);
  for (int k = 2; k <= NB; k <<= 1) {
    for (int j = k >> 1; j > 0; j >>= 1) {
      float partner;
      if (j < 64) {
        partner = __shfl_xor(v, j, 64);
      } else {
        __syncthreads();
        c_lds[tid] = v;
        __syncthreads();
        partner = c_lds[tid ^ j];
      }
      const bool up = ((tid & k) == 0);
      const bool low = ((tid & j) == 0);
      v = (low == up) ? fminf(v, partner) : fmaxf(v, partner);
    }
  }
  __syncthreads();
  c_lds[tid] = v;
  d_lds[tid] = 0u;   // complement space: 0 == +inf
  __syncthreads();

  // ---- main body: masked sums + chamfer scatter ----
  float pe[ELEMS] = {p4.x, p4.y, p4.z, p4.w};
  float te[ELEMS] = {t4.x, t4.y, t4.z, t4.w};
  int me[ELEMS];
  if (bytemode) {
    uchar4 m4 = *(const uchar4*)((const unsigned char*)mask + base);
    me[0] = m4.x; me[1] = m4.y; me[2] = m4.z; me[3] = m4.w;
  } else {
    int4 m4 = *(const int4*)((const int*)mask + base);
    me[0] = m4.x; me[1] = m4.y; me[2] = m4.z; me[3] = m4.w;
  }

  double cnt = 0, ssq = 0, sd = 0, sd2 = 0, dir2 = 0;
#pragma unroll
  for (int e = 0; e < ELEMS; ++e) {
    const float pi = pe[e], ti = te[e];
    if (me[e]) {
      float diff = pi - ti;
      float d = logf(pi + 1e-10f) - logf(ti + 1e-10f);
      cnt += 1.0;
      ssq += (double)diff * (double)diff;
      sd  += (double)d;
      sd2 += (double)d * (double)d;
    }
    // largest k with c[k] <= ti
    int k = -1;
#pragma unroll
    for (int s = 128; s > 0; s >>= 1) {
      int nk = k + s;
      if (nk < NB && c_lds[nk] <= ti) k = nk;
    }
    float dl = (k >= 0)     ? ti - c_lds[k]     : 1e30f;
    float dr = (k + 1 < NB) ? c_lds[k + 1] - ti : 1e30f;
    if (k >= 0)     atomicMax(&d_lds[k],     ~__float_as_uint(dl));
    if (k + 1 < NB) atomicMax(&d_lds[k + 1], ~__float_as_uint(dr));
    float dmin = fminf(dl, dr);
    dir2 += (double)dmin * (double)dmin;
  }

  __syncthreads();
  {
    unsigned int dv = d_lds[tid];
    if (dv) atomicMax(&gD[b * NB + tid], dv);
  }
  if ((blockIdx.x % BPB) == 0) {
    atomicExch((unsigned int*)&cs[b * NB + tid], __float_as_uint(c_lds[tid]));
  }

  double acc[5] = {cnt, ssq, sd, sd2, dir2};
#pragma unroll
  for (int i = 0; i < 5; ++i) {
    double r = wsum64(acc[i]);
    if (lane == 0) shred[wid][i] = r;
  }
  __syncthreads();
  if (tid < 5) {
    atomicAdd(&sums[tid],
              shred[0][tid] + shred[1][tid] + shred[2][tid] + shred[3][tid]);
  }

  // ---- ticket: wait for OWN atomics only (no L2-writeback fence) ----
  asm volatile("s_waitcnt vmcnt(0) lgkmcnt(0)" ::: "memory");
  __syncthreads();
  if (tid == 0)
    last_flag = (atomicAdd(ticket, 1u) == (unsigned)(MAIN_BLOCKS - 1)) ? 1u : 0u;
  __syncthreads();
  if (last_flag == 0u) return;

  // ---- finalizer: all reads via atomics (coherence-point loads) ----
  float cA[2][4], DA[2][4];
#pragma unroll
  for (int r = 0; r < 2; ++r) {
    const int bb = wid + r * 4;
#pragma unroll
    for (int i = 0; i < 4; ++i) {
      const int idx = bb * NB + lane * 4 + i;
      cA[r][i] = __uint_as_float(atomicOr((unsigned int*)&cs[idx], 0u));
      unsigned int s = atomicOr(&gD[idx], 0u);
      DA[r][i] = s ? __uint_as_float(~s) : FINF;
    }
  }

  double dir1 = 0.0;
#pragma unroll
  for (int r = 0; r < 2; ++r) {
    float c[4] = {cA[r][0], cA[r][1], cA[r][2], cA[r][3]};
    float D[4] = {DA[r][0], DA[r][1], DA[r][2], DA[r][3]};

    // prefix-inclusive min of (D - c)
    float pa[4];
    pa[0] = D[0] - c[0];
    pa[1] = fminf(pa[0], D[1] - c[1]);
    pa[2] = fminf(pa[1], D[2] - c[2]);
    pa[3] = fminf(pa[2], D[3] - c[3]);
    float s1 = pa[3];
#pragma unroll
    for (int off = 1; off < 64; off <<= 1) {
      float u = __shfl_up(s1, off, 64);
      if (lane >= off) s1 = fminf(s1, u);
    }
    float exL = __shfl_up(s1, 1, 64);
    if (lane == 0) exL = FINF;

    // suffix-inclusive min of (D + c)
    float sb[4];
    sb[3] = D[3] + c[3];
    sb[2] = fminf(sb[3], D[2] + c[2]);
    sb[1] = fminf(sb[2], D[1] + c[1]);
    sb[0] = fminf(sb[1], D[0] + c[0]);
    float s2 = sb[0];
#pragma unroll
    for (int off = 1; off < 64; off <<= 1) {
      float u = __shfl_down(s2, off, 64);
      if (lane + off < 64) s2 = fminf(s2, u);
    }
    float exR = __shfl_down(s2, 1, 64);
    if (lane == 63) exR = FINF;

#pragma unroll
    for (int i = 0; i < 4; ++i) {
      float pref = fminf(exL, pa[i]);
      float suf  = fminf(exR, sb[i]);
      float dist = fminf(pref + c[i], suf - c[i]);
      dir1 += (double)dist * (double)dist;
    }
  }

  dir1 = wsum64(dir1);
  if (lane == 0) shred[wid][0] = dir1;
  __syncthreads();
  if (tid == 0) {
    double d1 = shred[0][0] + shred[1][0] + shred[2][0] + shred[3][0];
    double cnt_ = atomicAdd(&sums[0], 0.0);
    double ssq_ = atomicAdd(&sums[1], 0.0);
    double sd_  = atomicAdd(&sums[2], 0.0);
    double sd2_ = atomicAdd(&sums[3], 0.0);
    double d2_  = atomicAdd(&sums[4], 0.0);
    double l2 = sqrt(ssq_ / cnt_);
    double dm = sd_ / cnt_, d2m = sd2_ / cnt_;
    double silog = 10.0 * sqrt(d2m - 0.85 * dm * dm);
    double chamfer = (d1 + d2_) / (double)NBATCH;
    out[0] = (float)(l2 + silog + chamfer);
  }
}

extern "C" void kernel_launch(void* const* d_in, const int* in_sizes, int n_in,
                              void* d_out, int out_size, void* d_ws, size_t ws_size,
                              hipStream_t stream) {
  const float* pred  = (const float*)d_in[0];
  const float* targ  = (const float*)d_in[1];
  const float* edges = (const float*)d_in[2];
  const void*  mask  = d_in[3];

  char* ws = (char*)d_ws;
  double* sums         = (double*)ws;
  unsigned int* ticket = (unsigned int*)(ws + 40);
  unsigned int* gD     = (unsigned int*)(ws + 64);
  float* cs            = (float*)(ws + 8256);

  hipMemsetAsync(ws, 0, 8256, stream);
  k_fused<<<MAIN_BLOCKS, NB, 0, stream>>>(pred, targ, mask, edges,
                                          sums, ticket, gD, cs, (float*)d_out);
}

// Round 6
// 24.851 us; speedup vs baseline: 2.2407x; 1.4015x over previous
//
#include <hip/hip_runtime.h>
#include <math.h>

#define HW     76800
#define NBATCH 8
#define NB     256
#define NEDGE  257
#define ELEMS  12
#define XBLKS  25                      // HW / (256*ELEMS) exactly
#define MAIN_BLOCKS (XBLKS * NBATCH)   // 200 blocks <= 256 CUs: one generation
#define FINF 3.402823466e+38f

// ws layout (all (re)initialized by k_prep every call — no memset node):
//   [0,320)      double sums[40]   5 per batch: {cnt,ssq,sd,sd2,dir2}
//   [320,324)    uint ticket
//   [324,328)    uint flag         1 = mask is bytes, 0 = int32
//   [512,8704)   uint gD[8][256]   complement-space bracket mins (0 == +inf)
//   [8704,16896) float cs[8][256]  sorted centers (plain stores; inter-kernel
//                                  coherence via runtime dispatch-boundary fences)

__device__ __forceinline__ double wsum64(double v) {
#pragma unroll
  for (int o = 32; o > 0; o >>= 1) v += __shfl_down(v, o, 64);
  return v;
}

__device__ __forceinline__ unsigned int nzb(unsigned int w) {
  return ((w & 0xFFu) != 0u) + (((w >> 8) & 0xFFu) != 0u) +
         (((w >> 16) & 0xFFu) != 0u) + ((w >> 24) != 0u);
}

__global__ void __launch_bounds__(256) k_prep(
    const float* __restrict__ edges, const unsigned char* __restrict__ mask,
    double* __restrict__ sums, unsigned int* __restrict__ ticket,
    unsigned int* __restrict__ flag, unsigned int* __restrict__ gD,
    float* __restrict__ cs) {
  const int tid = threadIdx.x, b = blockIdx.x;
  if (b < NBATCH) {
    __shared__ float s[NB];
    float v = 0.5f * (edges[b * NEDGE + tid] + edges[b * NEDGE + tid + 1]);
    for (int k = 2; k <= NB; k <<= 1) {
      for (int j = k >> 1; j > 0; j >>= 1) {
        float partner;
        if (j < 64) {
          partner = __shfl_xor(v, j, 64);
        } else {
          __syncthreads();
          s[tid] = v;
          __syncthreads();
          partner = s[tid ^ j];
        }
        const bool up = ((tid & k) == 0);
        const bool low = ((tid & j) == 0);
        v = (low == up) ? fminf(v, partner) : fmaxf(v, partner);
      }
    }
    cs[b * NB + tid] = v;
    gD[b * NB + tid] = 0u;             // complement space: 0 == +inf
  } else {
    // mask dtype detect from first 4KB: bool ~2048/4096 nonzero bytes, int32 ~512
    uint4 raw = ((const uint4*)mask)[tid];
    unsigned int c = nzb(raw.x) + nzb(raw.y) + nzb(raw.z) + nzb(raw.w);
#pragma unroll
    for (int o = 32; o > 0; o >>= 1) c += __shfl_down(c, o, 64);
    __shared__ unsigned int sh[4];
    if ((tid & 63) == 0) sh[tid >> 6] = c;
    __syncthreads();
    if (tid == 0) *flag = ((sh[0] + sh[1] + sh[2] + sh[3]) > 1024u) ? 1u : 0u;
    if (tid < 40) sums[tid] = 0.0;
    if (tid == 40) *ticket = 0u;
  }
}

__global__ void __launch_bounds__(256) k_main(
    const float* __restrict__ p, const float* __restrict__ t,
    const void* __restrict__ mask, const unsigned int* __restrict__ flag,
    const float* __restrict__ cs, double* __restrict__ sums,
    unsigned int* __restrict__ gD, unsigned int* __restrict__ ticket,
    float* __restrict__ out) {
  __shared__ float c_lds[NB];
  __shared__ unsigned int d_lds[NB];
  __shared__ double shred[4][5];
  __shared__ double fin[40];
  __shared__ unsigned int last_flag;

  const int tid = threadIdx.x, lane = tid & 63, wid = tid >> 6;
  const int b = blockIdx.y;
  const int ebase = b * HW + blockIdx.x * (NB * ELEMS) + tid * ELEMS;

  c_lds[tid] = cs[b * NB + tid];
  d_lds[tid] = 0u;
  __syncthreads();
  // register pivots: levels s=256,128,64,32 of the search become VALU-only
  const float c255 = c_lds[255], c127 = c_lds[127], c63 = c_lds[63],
              c191 = c_lds[191], c31 = c_lds[31], c95 = c_lds[95],
              c159 = c_lds[159], c223 = c_lds[223];

  // ---- vector loads: 48B/thread of p and t, 12 or 48 bytes of mask ----
  float pe[ELEMS], te[ELEMS];
  int me[ELEMS];
  {
    const float4* pp = (const float4*)(p + ebase);
    const float4* tt = (const float4*)(t + ebase);
#pragma unroll
    for (int q = 0; q < 3; ++q) {
      float4 a = pp[q], c = tt[q];
      pe[q * 4 + 0] = a.x; pe[q * 4 + 1] = a.y; pe[q * 4 + 2] = a.z; pe[q * 4 + 3] = a.w;
      te[q * 4 + 0] = c.x; te[q * 4 + 1] = c.y; te[q * 4 + 2] = c.z; te[q * 4 + 3] = c.w;
    }
  }
  if (*flag) {
    const unsigned int* mp = (const unsigned int*)((const unsigned char*)mask + ebase);
    unsigned int w[3] = {mp[0], mp[1], mp[2]};
#pragma unroll
    for (int e = 0; e < ELEMS; ++e) me[e] = (w[e >> 2] >> ((e & 3) * 8)) & 0xFFu;
  } else {
    const int4* mp = (const int4*)((const int*)mask + ebase);
#pragma unroll
    for (int q = 0; q < 3; ++q) {
      int4 m4 = mp[q];
      me[q * 4 + 0] = m4.x; me[q * 4 + 1] = m4.y; me[q * 4 + 2] = m4.z; me[q * 4 + 3] = m4.w;
    }
  }

  double cnt = 0, ssq = 0, sd = 0, sd2 = 0, dir2 = 0;
#pragma unroll
  for (int e = 0; e < ELEMS; ++e) {
    const float pi = pe[e], ti = te[e];
    if (me[e]) {
      float diff = pi - ti;
      float d = logf(pi + 1e-10f) - logf(ti + 1e-10f);
      cnt += 1.0;
      ssq += (double)diff * (double)diff;
      sd  += (double)d;
      sd2 += (double)d * (double)d;
    }
    // largest k with c[k] <= ti; k=-1 if none. Levels 256..32 from registers.
    int k = -1;
    if (c127 <= ti) k = 127;
    { float pr = (k == 127) ? c191 : c63; if (pr <= ti) k += 64; }
    { int idx = (k + 32) >> 6;  // 0..3 for k in {-1,63,127,191}
      float pr = (idx >= 2) ? ((idx == 3) ? c223 : c159)
                            : ((idx == 1) ? c95 : c31);
      if (pr <= ti) k += 32; }
    if (c255 <= ti) k = 255;   // the level the old s=128 loop could never reach
#pragma unroll
    for (int s = 16; s > 0; s >>= 1) {
      int nk = k + s;
      if (nk < NB && c_lds[nk] <= ti) k = nk;
    }
    float dl = (k >= 0)     ? ti - c_lds[k]     : FINF;  // >= 0
    float dr = (k + 1 < NB) ? c_lds[k + 1] - ti : FINF;  // >  0
    if (k >= 0)     atomicMax(&d_lds[k],     ~__float_as_uint(dl));
    if (k + 1 < NB) atomicMax(&d_lds[k + 1], ~__float_as_uint(dr));
    float dmin = fminf(dl, dr);
    dir2 += (double)dmin * (double)dmin;
  }

  __syncthreads();
  {
    unsigned int dv = d_lds[tid];
    if (dv) atomicMax(&gD[b * NB + tid], dv);
  }

  double acc[5] = {cnt, ssq, sd, sd2, dir2};
#pragma unroll
  for (int i = 0; i < 5; ++i) {
    double r = wsum64(acc[i]);
    if (lane == 0) shred[wid][i] = r;
  }
  __syncthreads();
  if (tid < 5) {
    atomicAdd(&sums[b * 5 + tid],
              shred[0][tid] + shred[1][tid] + shred[2][tid] + shred[3][tid]);
  }

  // ---- ticket: wait only for OWN atomics (no L2-writeback fence) ----
  asm volatile("s_waitcnt vmcnt(0) lgkmcnt(0)" ::: "memory");
  __syncthreads();
  if (tid == 0)
    last_flag = (atomicAdd(ticket, 1u) == (unsigned)(MAIN_BLOCKS - 1)) ? 1u : 0u;
  __syncthreads();
  if (last_flag == 0u) return;

  // ---- finalizer (last block): atomic reads for intra-kernel data ----
  if (tid < 40) fin[tid] = atomicAdd(&sums[tid], 0.0);

  double dir1 = 0.0;
#pragma unroll
  for (int r = 0; r < 2; ++r) {
    const int bb = wid + r * 4;
    float c[4], D[4];
#pragma unroll
    for (int i = 0; i < 4; ++i) {
      const int idx = bb * NB + lane * 4 + i;
      c[i] = cs[idx];                              // written by k_prep: plain ok
      unsigned int s = atomicOr(&gD[idx], 0u);     // written intra-kernel: atomic
      D[i] = s ? __uint_as_float(~s) : FINF;
    }

    float pa[4];
    pa[0] = D[0] - c[0];
    pa[1] = fminf(pa[0], D[1] - c[1]);
    pa[2] = fminf(pa[1], D[2] - c[2]);
    pa[3] = fminf(pa[2], D[3] - c[3]);
    float s1 = pa[3];
#pragma unroll
    for (int off = 1; off < 64; off <<= 1) {
      float u = __shfl_up(s1, off, 64);
      if (lane >= off) s1 = fminf(s1, u);
    }
    float exL = __shfl_up(s1, 1, 64);
    if (lane == 0) exL = FINF;

    float sb[4];
    sb[3] = D[3] + c[3];
    sb[2] = fminf(sb[3], D[2] + c[2]);
    sb[1] = fminf(sb[2], D[1] + c[1]);
    sb[0] = fminf(sb[1], D[0] + c[0]);
    float s2 = sb[0];
#pragma unroll
    for (int off = 1; off < 64; off <<= 1) {
      float u = __shfl_down(s2, off, 64);
      if (lane + off < 64) s2 = fminf(s2, u);
    }
    float exR = __shfl_down(s2, 1, 64);
    if (lane == 63) exR = FINF;

#pragma unroll
    for (int i = 0; i < 4; ++i) {
      float pref = fminf(exL, pa[i]);
      float suf  = fminf(exR, sb[i]);
      float dist = fminf(pref + c[i], suf - c[i]);
      dir1 += (double)dist * (double)dist;
    }
  }

  dir1 = wsum64(dir1);
  if (lane == 0) shred[wid][0] = dir1;
  __syncthreads();
  if (tid == 0) {
    double d1 = shred[0][0] + shred[1][0] + shred[2][0] + shred[3][0];
    double cnt_ = 0, ssq_ = 0, sd_ = 0, sd2_ = 0, d2_ = 0;
#pragma unroll
    for (int bb = 0; bb < NBATCH; ++bb) {
      cnt_ += fin[bb * 5 + 0]; ssq_ += fin[bb * 5 + 1];
      sd_  += fin[bb * 5 + 2]; sd2_ += fin[bb * 5 + 3];
      d2_  += fin[bb * 5 + 4];
    }
    double l2 = sqrt(ssq_ / cnt_);
    double dm = sd_ / cnt_, d2m = sd2_ / cnt_;
    double silog = 10.0 * sqrt(d2m - 0.85 * dm * dm);
    double chamfer = (d1 + d2_) / (double)NBATCH;
    out[0] = (float)(l2 + silog + chamfer);
  }
}

extern "C" void kernel_launch(void* const* d_in, const int* in_sizes, int n_in,
                              void* d_out, int out_size, void* d_ws, size_t ws_size,
                              hipStream_t stream) {
  const float* pred  = (const float*)d_in[0];
  const float* targ  = (const float*)d_in[1];
  const float* edges = (const float*)d_in[2];
  const void*  mask  = d_in[3];

  char* ws = (char*)d_ws;
  double* sums         = (double*)ws;
  unsigned int* ticket = (unsigned int*)(ws + 320);
  unsigned int* flag   = (unsigned int*)(ws + 324);
  unsigned int* gD     = (unsigned int*)(ws + 512);
  float* cs            = (float*)(ws + 8704);

  k_prep<<<NBATCH + 1, NB, 0, stream>>>(edges, (const unsigned char*)mask,
                                        sums, ticket, flag, gD, cs);
  k_main<<<dim3(XBLKS, NBATCH), NB, 0, stream>>>(pred, targ, mask, flag, cs,
                                                 sums, gD, ticket, (float*)d_out);
}

// Round 7
// 21.723 us; speedup vs baseline: 2.5633x; 1.1440x over previous
//
#include <hip/hip_runtime.h>
#include <math.h>

#define HW     76800
#define NBATCH 8
#define NB     256
#define NEDGE  257
#define ELEMS  12
#define XBLKS  25                      // HW / (256*ELEMS) exactly
#define MAIN_BLOCKS (XBLKS * NBATCH)   // 200 blocks <= 256 CUs: one generation
#define FINF 3.402823466e+38f

// ws layout (all (re)initialized by k_prep every call — no memset node):
//   [0,320)        double sums[40]   5 per batch: {cnt,ssq,sd,sd2,dir2}
//   [320,324)      uint ticket
//   [324,328)      uint flag          1 = mask is bytes, 0 = int32
//   [512,8704)     uint gD[8][256]    complement-space bracket mins (0 == +inf)
//   [8704,16896)   float cs[8][256]   sorted centers
//   [16896,33280)  float2 gLut[8][256] {c[k], k} for largest k with c[k] <= q/256

__device__ __forceinline__ float wsum32(float v) {
#pragma unroll
  for (int o = 32; o > 0; o >>= 1) v += __shfl_down(v, o, 64);
  return v;
}

__device__ __forceinline__ unsigned int nzb(unsigned int w) {
  return ((w & 0xFFu) != 0u) + (((w >> 8) & 0xFFu) != 0u) +
         (((w >> 16) & 0xFFu) != 0u) + ((w >> 24) != 0u);
}

__global__ void __launch_bounds__(256) k_prep(
    const float* __restrict__ edges, const unsigned char* __restrict__ mask,
    double* __restrict__ sums, unsigned int* __restrict__ ticket,
    unsigned int* __restrict__ flag, unsigned int* __restrict__ gD,
    float* __restrict__ cs, float2* __restrict__ gLut) {
  const int tid = threadIdx.x, b = blockIdx.x;
  if (b < NBATCH) {
    __shared__ float s[NB];
    float v = 0.5f * (edges[b * NEDGE + tid] + edges[b * NEDGE + tid + 1]);
    for (int k = 2; k <= NB; k <<= 1) {
      for (int j = k >> 1; j > 0; j >>= 1) {
        float partner;
        if (j < 64) {
          partner = __shfl_xor(v, j, 64);
        } else {
          __syncthreads();
          s[tid] = v;
          __syncthreads();
          partner = s[tid ^ j];
        }
        const bool up = ((tid & k) == 0);
        const bool low = ((tid & j) == 0);
        v = (low == up) ? fminf(v, partner) : fmaxf(v, partner);
      }
    }
    cs[b * NB + tid] = v;
    gD[b * NB + tid] = 0u;             // complement space: 0 == +inf
    __syncthreads();
    s[tid] = v;
    __syncthreads();
    // LUT: largest k with s[k] <= tid/256 (exact lower-bound start for search)
    const float x = (float)tid * 0.00390625f;
    int k = -1;
    if (s[255] <= x) {
      k = 255;
    } else {
#pragma unroll
      for (int st = 128; st > 0; st >>= 1) {
        int nk = k + st;
        if (nk < 255 && s[nk] <= x) k = nk;
      }
    }
    float ck = (k >= 0) ? s[k] : -FINF;
    gLut[b * NB + tid] = make_float2(ck, __int_as_float(k));
  } else {
    // mask dtype detect from first 4KB: bool ~2048/4096 nonzero bytes, int32 ~512
    uint4 raw = ((const uint4*)mask)[tid];
    unsigned int c = nzb(raw.x) + nzb(raw.y) + nzb(raw.z) + nzb(raw.w);
#pragma unroll
    for (int o = 32; o > 0; o >>= 1) c += __shfl_down(c, o, 64);
    __shared__ unsigned int sh[4];
    if ((tid & 63) == 0) sh[tid >> 6] = c;
    __syncthreads();
    if (tid == 0) *flag = ((sh[0] + sh[1] + sh[2] + sh[3]) > 1024u) ? 1u : 0u;
    if (tid < 40) sums[tid] = 0.0;
    if (tid == 40) *ticket = 0u;
  }
}

__global__ void __launch_bounds__(256) k_main(
    const float* __restrict__ p, const float* __restrict__ t,
    const void* __restrict__ mask, const unsigned int* __restrict__ flag,
    const float* __restrict__ cs, const float2* __restrict__ gLut,
    double* __restrict__ sums, unsigned int* __restrict__ gD,
    unsigned int* __restrict__ ticket, float* __restrict__ out) {
  __shared__ float c_lds[NB + 1];        // +inf sentinel at [256]
  __shared__ float2 lut_lds[NB];
  __shared__ unsigned int d_lds[NB + 2]; // center j at [j+1]; 0 and 257 dummies
  __shared__ float shred[4][5];
  __shared__ double dpart[4];
  __shared__ double fin[40];
  __shared__ unsigned int last_flag;

  const int tid = threadIdx.x, lane = tid & 63, wid = tid >> 6;
  const int b = blockIdx.y;
  const int ebase = b * HW + blockIdx.x * (NB * ELEMS) + tid * ELEMS;

  c_lds[tid] = cs[b * NB + tid];
  lut_lds[tid] = gLut[b * NB + tid];
  d_lds[tid] = 0u;
  if (tid < 2) d_lds[NB + tid] = 0u;
  if (tid == 0) c_lds[NB] = FINF;
  __syncthreads();

  // ---- vector loads: 48B/thread of p and t, 12 or 48 bytes of mask ----
  float pe[ELEMS], te[ELEMS];
  int me[ELEMS];
  {
    const float4* pp = (const float4*)(p + ebase);
    const float4* tt = (const float4*)(t + ebase);
#pragma unroll
    for (int q = 0; q < 3; ++q) {
      float4 a = pp[q], c = tt[q];
      pe[q * 4 + 0] = a.x; pe[q * 4 + 1] = a.y; pe[q * 4 + 2] = a.z; pe[q * 4 + 3] = a.w;
      te[q * 4 + 0] = c.x; te[q * 4 + 1] = c.y; te[q * 4 + 2] = c.z; te[q * 4 + 3] = c.w;
    }
  }
  if (*flag) {
    const unsigned int* mp = (const unsigned int*)((const unsigned char*)mask + ebase);
    unsigned int w[3] = {mp[0], mp[1], mp[2]};
#pragma unroll
    for (int e = 0; e < ELEMS; ++e) me[e] = (w[e >> 2] >> ((e & 3) * 8)) & 0xFFu;
  } else {
    const int4* mp = (const int4*)((const int*)mask + ebase);
#pragma unroll
    for (int q = 0; q < 3; ++q) {
      int4 m4 = mp[q];
      me[q * 4 + 0] = m4.x; me[q * 4 + 1] = m4.y; me[q * 4 + 2] = m4.z; me[q * 4 + 3] = m4.w;
    }
  }

  // ---- masked reductions (f32 partials, int count) ----
  int cnt = 0;
  float ssq = 0.f, sd = 0.f, sd2 = 0.f, dir2 = 0.f;
#pragma unroll
  for (int e = 0; e < ELEMS; ++e) {
    if (me[e]) {
      float diff = pe[e] - te[e];
      float d = logf(pe[e] + 1e-10f) - logf(te[e] + 1e-10f);
      cnt += 1;
      ssq += diff * diff;
      sd  += d;
      sd2 += d * d;
    }
  }

  // ---- chamfer: LUT start (batched independent reads), short forward scan ----
  int   kk[ELEMS];
  float ck[ELEMS], c1[ELEMS];
#pragma unroll
  for (int e = 0; e < ELEMS; ++e) {
    int q = (int)(te[e] * 256.0f);
    q = (q < 0) ? 0 : ((q > 255) ? 255 : q);
    float2 lu = lut_lds[q];
    ck[e] = lu.x;
    kk[e] = __float_as_int(lu.y);
  }
#pragma unroll
  for (int e = 0; e < ELEMS; ++e) c1[e] = c_lds[kk[e] + 1];
#pragma unroll
  for (int e = 0; e < ELEMS; ++e) {
    const float ti = te[e];
    int k = kk[e];
    float c0 = ck[e], cn = c1[e];
    while (cn <= ti) { ++k; c0 = cn; cn = c_lds[k + 1]; }  // c_lds[256]=inf stops
    float dl = ti - c0;   // +inf when k==-1 (c0=-inf)
    float dr = cn - ti;   // +inf when k==255
    atomicMax(&d_lds[k + 1], ~__float_as_uint(dl));  // k==-1 -> dummy slot 0
    atomicMax(&d_lds[k + 2], ~__float_as_uint(dr));  // k==255 -> dummy slot 257
    float dm = fminf(dl, dr);
    dir2 += dm * dm;
  }

  __syncthreads();
  {
    unsigned int dv = d_lds[tid + 1];
    if (dv) atomicMax(&gD[b * NB + tid], dv);
  }

  // ---- block reduction: 5 f32 wave-sums -> f64 atomics ----
  float acc[5] = {(float)cnt, ssq, sd, sd2, dir2};
#pragma unroll
  for (int i = 0; i < 5; ++i) {
    float r = wsum32(acc[i]);
    if (lane == 0) shred[wid][i] = r;
  }
  __syncthreads();
  if (tid < 5) {
    atomicAdd(&sums[b * 5 + tid],
              (double)(shred[0][tid] + shred[1][tid] + shred[2][tid] + shred[3][tid]));
  }

  // ---- ticket: wait only for OWN atomics (no L2-writeback fence) ----
  asm volatile("s_waitcnt vmcnt(0) lgkmcnt(0)" ::: "memory");
  __syncthreads();
  if (tid == 0)
    last_flag = (atomicAdd(ticket, 1u) == (unsigned)(MAIN_BLOCKS - 1)) ? 1u : 0u;
  __syncthreads();
  if (last_flag == 0u) return;

  // ---- finalizer (last block): distance transform over centers ----
  if (tid < 40) fin[tid] = atomicAdd(&sums[tid], 0.0);

  double dir1 = 0.0;
#pragma unroll
  for (int r = 0; r < 2; ++r) {
    const int bb = wid + r * 4;
    float c[4], D[4];
#pragma unroll
    for (int i = 0; i < 4; ++i) {
      const int idx = bb * NB + lane * 4 + i;
      c[i] = cs[idx];                              // k_prep data: plain read ok
      unsigned int s = atomicOr(&gD[idx], 0u);     // intra-kernel data: atomic
      D[i] = s ? __uint_as_float(~s) : FINF;
    }

    float pa[4];
    pa[0] = D[0] - c[0];
    pa[1] = fminf(pa[0], D[1] - c[1]);
    pa[2] = fminf(pa[1], D[2] - c[2]);
    pa[3] = fminf(pa[2], D[3] - c[3]);
    float s1 = pa[3];
#pragma unroll
    for (int off = 1; off < 64; off <<= 1) {
      float u = __shfl_up(s1, off, 64);
      if (lane >= off) s1 = fminf(s1, u);
    }
    float exL = __shfl_up(s1, 1, 64);
    if (lane == 0) exL = FINF;

    float sb[4];
    sb[3] = D[3] + c[3];
    sb[2] = fminf(sb[3], D[2] + c[2]);
    sb[1] = fminf(sb[2], D[1] + c[1]);
    sb[0] = fminf(sb[1], D[0] + c[0]);
    float s2 = sb[0];
#pragma unroll
    for (int off = 1; off < 64; off <<= 1) {
      float u = __shfl_down(s2, off, 64);
      if (lane + off < 64) s2 = fminf(s2, u);
    }
    float exR = __shfl_down(s2, 1, 64);
    if (lane == 63) exR = FINF;

#pragma unroll
    for (int i = 0; i < 4; ++i) {
      float pref = fminf(exL, pa[i]);
      float suf  = fminf(exR, sb[i]);
      float dist = fminf(pref + c[i], suf - c[i]);
      dir1 += (double)dist * (double)dist;
    }
  }

#pragma unroll
  for (int o = 32; o > 0; o >>= 1) dir1 += __shfl_down(dir1, o, 64);
  if (lane == 0) dpart[wid] = dir1;
  __syncthreads();
  if (tid == 0) {
    double d1 = dpart[0] + dpart[1] + dpart[2] + dpart[3];
    double cnt_ = 0, ssq_ = 0, sd_ = 0, sd2_ = 0, d2_ = 0;
#pragma unroll
    for (int bb = 0; bb < NBATCH; ++bb) {
      cnt_ += fin[bb * 5 + 0]; ssq_ += fin[bb * 5 + 1];
      sd_  += fin[bb * 5 + 2]; sd2_ += fin[bb * 5 + 3];
      d2_  += fin[bb * 5 + 4];
    }
    double l2 = sqrt(ssq_ / cnt_);
    double dm = sd_ / cnt_, d2m = sd2_ / cnt_;
    double silog = 10.0 * sqrt(d2m - 0.85 * dm * dm);
    double chamfer = (d1 + d2_) / (double)NBATCH;
    out[0] = (float)(l2 + silog + chamfer);
  }
}

extern "C" void kernel_launch(void* const* d_in, const int* in_sizes, int n_in,
                              void* d_out, int out_size, void* d_ws, size_t ws_size,
                              hipStream_t stream) {
  const float* pred  = (const float*)d_in[0];
  const float* targ  = (const float*)d_in[1];
  const float* edges = (const float*)d_in[2];
  const void*  mask  = d_in[3];

  char* ws = (char*)d_ws;
  double* sums         = (double*)ws;
  unsigned int* ticket = (unsigned int*)(ws + 320);
  unsigned int* flag   = (unsigned int*)(ws + 324);
  unsigned int* gD     = (unsigned int*)(ws + 512);
  float* cs            = (float*)(ws + 8704);
  float2* gLut         = (float2*)(ws + 16896);

  k_prep<<<NBATCH + 1, NB, 0, stream>>>(edges, (const unsigned char*)mask,
                                        sums, ticket, flag, gD, cs, gLut);
  k_main<<<dim3(XBLKS, NBATCH), NB, 0, stream>>>(pred, targ, mask, flag, cs, gLut,
                                                 sums, gD, ticket, (float*)d_out);
}